// Round 22
// baseline (135.303 us; speedup 1.0000x reference)
//
#include <hip/hip_runtime.h>

// MonarchLinear as one dense bf16-MFMA GEMM (round 22).
//   W[j][k] = L[r][l][p]*R[l][s][r] (j=s*68+l, k=r*68+p<256); out = x @ W^T + bias.
// r21 main (~90us) was L2-bound: 2048 blocks x 1.18MB Wpk = 2.4GB L2 reads (~70us).
// This round: grid 256 (1 block/CU), BM=64 tokens, full-N sweep -> W/block =
// 2.36MB, chip total 604MB (~17us, hidden under the 46us write drain); Wpk fits
// each XCD L2 so steady-state W reads are L2 hits. A-frags 128 VGPR
// (launch_bounds(256,1): no spill cap), per-wave LDS transpose epilogue
// (no barriers), 1KB-contiguous f4 stores. pack_w2 = r21 verbatim (proven).

typedef float f4 __attribute__((ext_vector_type(4)));
typedef short s8v __attribute__((ext_vector_type(8)));   // 8 bf16 = 4 VGPR

namespace {
constexpr int MM    = 68;
constexpr int IN_D  = 256;
constexpr int OUT_D = 4608;
constexpr int NTH   = 256;
constexpr int BM    = 64;            // tokens per block (4 MFMA row-tiles)
constexpr int EPW   = 20;            // ep row stride (f32): 16 + 4 pad
constexpr int NJT   = OUT_D / 16;    // 288 j-tiles
}

__device__ __forceinline__ unsigned short f2bf(float f) {
  unsigned int u = __float_as_uint(f);
  u += 0x7FFFu + ((u >> 16) & 1u);   // RNE
  return (unsigned short)(u >> 16);
}

// ---------- pack: Wpk in MFMA B-frag order (r21 verbatim, proven) ----------
__global__ __launch_bounds__(NTH, 1)
void pack_w2(const float* __restrict__ L, const float* __restrict__ R,
             unsigned short* __restrict__ Wpk)
{
  const int g    = blockIdx.x * 4 + (threadIdx.x >> 6);   // 0..2303
  const int lane = threadIdx.x & 63;
  const int jc   = g >> 3;
  const int ks   = g & 7;
  const int j    = jc * 16 + (lane & 15);
  const int s    = j / MM;
  const int l    = j - s * MM;
  const int k0   = ks * 32 + (lane >> 4) * 8;
  unsigned int h[4];
#pragma unroll
  for (int i2 = 0; i2 < 4; ++i2) {
    unsigned int w2[2];
#pragma unroll
    for (int e = 0; e < 2; ++e) {
      int k = k0 + i2 * 2 + e;
      int r = k / MM, p = k - r * MM;
      float w = L[(r * MM + l) * MM + p] * R[(l * MM + s) * MM + r];
      w2[e] = f2bf(w);
    }
    h[i2] = w2[0] | (w2[1] << 16);
  }
  uint4 v; v.x = h[0]; v.y = h[1]; v.z = h[2]; v.w = h[3];
  *(uint4*)(Wpk + ((size_t)g * 64 + lane) * 8) = v;
}

// ---------------- main GEMM: out = x @ W^T + bias ----------------
__global__ __launch_bounds__(NTH, 1)
void mono_gemm3(const float* __restrict__ x, const unsigned short* __restrict__ Wpk,
                const float* __restrict__ bias, float* __restrict__ out)
{
  __shared__ float ep[4][BM][EPW];     // per-WAVE transpose slices, 20,480 B
  const int tid  = threadIdx.x;
  const int lane = tid & 63;
  const int wv   = tid >> 6;
  const int lrow = lane & 15;
  const int lgrp = lane >> 4;
  const long tb  = (long)blockIdx.x * BM;

  // ---- A prologue: 64 tokens x K=256 bf16 frags (128 VGPR), proven layout ----
  // lane holds A[row=lane&15][k = ks*32 + (lane>>4)*8 + 0..7]
  s8v afr[4][8];
#pragma unroll
  for (int mt = 0; mt < 4; ++mt) {
#pragma unroll
    for (int ks = 0; ks < 8; ++ks) {
      const float* xp = x + (tb + mt * 16 + lrow) * IN_D + ks * 32 + lgrp * 8;
      f4 a = *(const f4*)(xp);
      f4 b = *(const f4*)(xp + 4);
      s8v t;
      t[0] = (short)f2bf(a.x); t[1] = (short)f2bf(a.y);
      t[2] = (short)f2bf(a.z); t[3] = (short)f2bf(a.w);
      t[4] = (short)f2bf(b.x); t[5] = (short)f2bf(b.y);
      t[6] = (short)f2bf(b.z); t[7] = (short)f2bf(b.w);
      afr[mt][ks] = t;
    }
  }

  float (*eps)[EPW] = ep[wv];          // this wave's private slice — no barriers

#pragma unroll 1
  for (int t = wv; t < NJT; t += 4) {  // 72 j-tiles per wave; CU-lockstep j order
    const int j0 = t * 16;
    // ---- W frags: lane-contiguous 1KB loads, L2-hit after warm-up ----
    uint4 bfr[8];
#pragma unroll
    for (int ks = 0; ks < 8; ++ks)
      bfr[ks] = *(const uint4*)(Wpk + (((size_t)t * 8 + ks) * 64 + lane) * 8);
    // ---- 32 MFMA: 4 token-tiles x 8 K-steps ----
    f4 acc0 = {0.f,0.f,0.f,0.f}, acc1 = {0.f,0.f,0.f,0.f};
    f4 acc2 = {0.f,0.f,0.f,0.f}, acc3 = {0.f,0.f,0.f,0.f};
#pragma unroll
    for (int ks = 0; ks < 8; ++ks) {
      s8v bf = *(s8v*)&bfr[ks];
      acc0 = __builtin_amdgcn_mfma_f32_16x16x32_bf16(afr[0][ks], bf, acc0, 0, 0, 0);
      acc1 = __builtin_amdgcn_mfma_f32_16x16x32_bf16(afr[1][ks], bf, acc1, 0, 0, 0);
      acc2 = __builtin_amdgcn_mfma_f32_16x16x32_bf16(afr[2][ks], bf, acc2, 0, 0, 0);
      acc3 = __builtin_amdgcn_mfma_f32_16x16x32_bf16(afr[3][ks], bf, acc3, 0, 0, 0);
    }
    // ---- transpose via per-wave LDS: D col=lane&15, row=(lane>>4)*4+q ----
#pragma unroll
    for (int q = 0; q < 4; ++q) {
      eps[ 0 + lgrp * 4 + q][lrow] = acc0[q];   // <=2-way banks: free
      eps[16 + lgrp * 4 + q][lrow] = acc1[q];
      eps[32 + lgrp * 4 + q][lrow] = acc2[q];
      eps[48 + lgrp * 4 + q][lrow] = acc3[q];
    }
    // ---- coalesced stores: 16 rows x 64B full-line chunks per instr ----
    const f4 bv = *(const f4*)(bias + j0 + (lane & 3) * 4);
#pragma unroll
    for (int sw = 0; sw < 4; ++sw) {
      const int rr = sw * 16 + (lane >> 2);
      f4 v = *(const f4*)(&eps[rr][(lane & 3) * 4]);
      f4 o;
      o.x = v.x + bv.x; o.y = v.y + bv.y; o.z = v.z + bv.z; o.w = v.w + bv.w;
      *(f4*)(out + (tb + rr) * OUT_D + j0 + (lane & 3) * 4) = o;
    }
  }
}

// ---------------- fallback (ws too small): r13 fused fp32 kernel ----------------
namespace {
constexpr int TTF  = 16;
constexpr int XROW = IN_D + 4;
constexpr int TPAD = 4 * MM + 4;
}
template <int P4M>
__device__ __forceinline__ void phaseA_f(const float* xls, const float* Lrow0, float* t1w)
{
  float acc[17];
#pragma unroll
  for (int li = 0; li < 17; ++li) acc[li] = 0.f;
#pragma unroll 1
  for (int p4 = 0; p4 < P4M; ++p4) {
    f4 xv = *(const f4*)(xls + 4 * p4);
    f4 Lv[17];
#pragma unroll
    for (int li = 0; li < 17; ++li) Lv[li] = *(const f4*)(Lrow0 + (size_t)li * MM + 4 * p4);
#pragma unroll
    for (int li = 0; li < 17; ++li) {
      acc[li] = fmaf(xv.x, Lv[li].x, acc[li]); acc[li] = fmaf(xv.y, Lv[li].y, acc[li]);
      acc[li] = fmaf(xv.z, Lv[li].z, acc[li]); acc[li] = fmaf(xv.w, Lv[li].w, acc[li]);
    }
  }
#pragma unroll
  for (int li = 0; li < 17; ++li) t1w[li] = acc[li];
}
__global__ __launch_bounds__(NTH, 4)
void monarch_fused(const float* __restrict__ x, const float* __restrict__ L,
                   const float* __restrict__ R, const float* __restrict__ bias,
                   float* __restrict__ out)
{
  __shared__ float xs[TTF * XROW];
  __shared__ float t1s[TTF * TPAD];
  const int tid = threadIdx.x;
  const long tb = (long)blockIdx.x * TTF;
#pragma unroll
  for (int k = 0; k < (TTF * IN_D / 4) / NTH; ++k) {
    int i = k * NTH + tid; int tok = i >> 6; int pos = i & 63;
    *(f4*)(&xs[tok * XROW + 4 * pos]) = *(const f4*)(x + (tb + tok) * IN_D + 4 * pos);
  }
  __syncthreads();
  {
    const int tok = tid & 15; const int seg = tid >> 4;
    const int r = seg >> 2; const int lq = seg & 3;
    const float* xls = &xs[tok * XROW + r * MM];
    const float* Lrow0 = L + (size_t)(r * MM + lq * 17) * MM;
    float* t1w = &t1s[tok * TPAD + r * MM + lq * 17];
    if (r < 3) phaseA_f<17>(xls, Lrow0, t1w); else phaseA_f<13>(xls, Lrow0, t1w);
  }
  __syncthreads();
  {
    const int g = tid / 17; const int m = tid - g * 17; const int l4 = 4 * m;
#pragma unroll 1
    for (int j = 0; j < 5; ++j) {
      const int s = g + 15 * j;
      const bool act = (tid < 255) && (s < MM) && (s < MM - 1 || m < 13);
      const int scol = s * MM + l4;
      f4 R0, R1, R2, R3, bv;
      if (act) {
        R0 = *(const f4*)(R + (size_t)(l4 + 0) * (MM * MM) + (size_t)s * MM);
        R1 = *(const f4*)(R + (size_t)(l4 + 1) * (MM * MM) + (size_t)s * MM);
        R2 = *(const f4*)(R + (size_t)(l4 + 2) * (MM * MM) + (size_t)s * MM);
        R3 = *(const f4*)(R + (size_t)(l4 + 3) * (MM * MM) + (size_t)s * MM);
        bv = *(const f4*)(bias + scol);
      }
#pragma unroll 2
      for (int t = 0; t < TTF; ++t) {
        if (act) {
          const float* t1p = t1s + t * TPAD + l4;
          f4 a0 = *(const f4*)(t1p); f4 a1 = *(const f4*)(t1p + MM);
          f4 a2 = *(const f4*)(t1p + 2 * MM); f4 a3 = *(const f4*)(t1p + 3 * MM);
          f4 o;
          o.x = fmaf(a3.x, R0.w, fmaf(a2.x, R0.z, fmaf(a1.x, R0.y, fmaf(a0.x, R0.x, bv.x))));
          o.y = fmaf(a3.y, R1.w, fmaf(a2.y, R1.z, fmaf(a1.y, R1.y, fmaf(a0.y, R1.x, bv.y))));
          o.z = fmaf(a3.z, R2.w, fmaf(a2.z, R2.z, fmaf(a1.z, R2.y, fmaf(a0.z, R2.x, bv.z))));
          o.w = fmaf(a3.w, R3.w, fmaf(a2.w, R3.z, fmaf(a1.w, R3.y, fmaf(a0.w, R3.x, bv.w))));
          *(f4*)(out + (tb + t) * OUT_D + scol) = o;
        }
      }
    }
  }
}

extern "C" void kernel_launch(void* const* d_in, const int* in_sizes, int n_in,
                              void* d_out, int out_size, void* d_ws, size_t ws_size,
                              hipStream_t stream) {
  const float* x    = (const float*)d_in[0];
  const float* L    = (const float*)d_in[1];
  const float* R    = (const float*)d_in[2];
  const float* bias = (const float*)d_in[3];
  float* out = (float*)d_out;

  const int ntok = in_sizes[0] / IN_D;                       // 16384
  const size_t wb_bytes = (size_t)OUT_D * IN_D * sizeof(unsigned short);  // 2.36 MB

  if (ws_size >= wb_bytes) {
    unsigned short* Wpk = (unsigned short*)d_ws;
    pack_w2<<<576, NTH, 0, stream>>>(L, R, Wpk);             // 2304 frag-groups
    mono_gemm3<<<ntok / BM, NTH, 0, stream>>>(x, Wpk, bias, out);
  } else {
    monarch_fused<<<ntok / TTF, NTH, 0, stream>>>(x, L, R, bias, out);
  }
}

// Round 23
// 105.314 us; speedup vs baseline: 1.2848x; 1.2848x over previous
//
#include <hip/hip_runtime.h>

// MonarchLinear as one dense bf16-MFMA GEMM (round 23).
//   W[j][k] = L[r][l][p]*R[l][s][r] (j=s*68+l, k=r*68+p<256); out = x @ W^T + bias.
// r21 (12 waves/CU, W-traffic 1.2GB) ~90; r22 (W 604MB but 4 waves/CU, serial
// tile chain) ~120. This round has all three levers at once:
//  - BM=64 + j-half split: grid 512, W/block 1.18MB -> 604MB L2 (~17us, hides)
//  - launch_bounds(256,2): 2 blocks/CU = 8 waves/CU (VGPR cap 256, est ~240)
//  - ping-pong W prefetch (bA/bB named buffers): L2 latency hides under the
//    previous tile's 32 MFMA + epilogue.
// pack_w2 / A-prologue / per-wave LDS transpose epilogue: r21/r22-proven.

typedef float f4 __attribute__((ext_vector_type(4)));
typedef short s8v __attribute__((ext_vector_type(8)));   // 8 bf16 = 4 VGPR

namespace {
constexpr int MM    = 68;
constexpr int IN_D  = 256;
constexpr int OUT_D = 4608;
constexpr int NTH   = 256;
constexpr int BM    = 64;            // tokens per block (4 MFMA row-tiles)
constexpr int EPW   = 20;            // ep row stride (f32): 16 + 4 pad
constexpr int NJT   = OUT_D / 16;    // 288 j-tiles
constexpr int HJT   = NJT / 2;       // 144 j-tiles per half
}

__device__ __forceinline__ unsigned short f2bf(float f) {
  unsigned int u = __float_as_uint(f);
  u += 0x7FFFu + ((u >> 16) & 1u);   // RNE
  return (unsigned short)(u >> 16);
}

// ---------- pack: Wpk in MFMA B-frag order (r21/r22 verbatim, proven) ----------
__global__ __launch_bounds__(NTH, 1)
void pack_w2(const float* __restrict__ L, const float* __restrict__ R,
             unsigned short* __restrict__ Wpk)
{
  const int g    = blockIdx.x * 4 + (threadIdx.x >> 6);   // 0..2303
  const int lane = threadIdx.x & 63;
  const int jc   = g >> 3;
  const int ks   = g & 7;
  const int j    = jc * 16 + (lane & 15);
  const int s    = j / MM;
  const int l    = j - s * MM;
  const int k0   = ks * 32 + (lane >> 4) * 8;
  unsigned int h[4];
#pragma unroll
  for (int i2 = 0; i2 < 4; ++i2) {
    unsigned int w2[2];
#pragma unroll
    for (int e = 0; e < 2; ++e) {
      int k = k0 + i2 * 2 + e;
      int r = k / MM, p = k - r * MM;
      float w = L[(r * MM + l) * MM + p] * R[(l * MM + s) * MM + r];
      w2[e] = f2bf(w);
    }
    h[i2] = w2[0] | (w2[1] << 16);
  }
  uint4 v; v.x = h[0]; v.y = h[1]; v.z = h[2]; v.w = h[3];
  *(uint4*)(Wpk + ((size_t)g * 64 + lane) * 8) = v;
}

// ---------------- main GEMM: out = x @ W^T + bias ----------------
__global__ __launch_bounds__(NTH, 2)     // 2 blocks/CU = 8 waves; VGPR cap 256
void mono_gemm4(const float* __restrict__ x, const unsigned short* __restrict__ Wpk,
                const float* __restrict__ bias, float* __restrict__ out)
{
  __shared__ float ep[4][BM][EPW];       // per-WAVE transpose slices, 20,480 B
  const int tid  = threadIdx.x;
  const int lane = tid & 63;
  const int wv   = tid >> 6;
  const int lrow = lane & 15;
  const int lgrp = lane >> 4;
  const int tile = blockIdx.x >> 1;      // adjacent blocks share x-tile
  const int jh   = blockIdx.x & 1;       // j half
  const long tb  = (long)tile * BM;
  const int base = jh * HJT;

  // ---- A prologue: 64 tokens x K=256 bf16 frags (128 VGPR), proven layout ----
  s8v afr[4][8];
#pragma unroll
  for (int mt = 0; mt < 4; ++mt) {
#pragma unroll
    for (int ks = 0; ks < 8; ++ks) {
      const float* xp = x + (tb + mt * 16 + lrow) * IN_D + ks * 32 + lgrp * 8;
      f4 a = *(const f4*)(xp);
      f4 b = *(const f4*)(xp + 4);
      s8v t;
      t[0] = (short)f2bf(a.x); t[1] = (short)f2bf(a.y);
      t[2] = (short)f2bf(a.z); t[3] = (short)f2bf(a.w);
      t[4] = (short)f2bf(b.x); t[5] = (short)f2bf(b.y);
      t[6] = (short)f2bf(b.z); t[7] = (short)f2bf(b.w);
      afr[mt][ks] = t;
    }
  }

  float (*eps)[EPW] = ep[wv];            // this wave's private slice — no barriers

  auto loadW = [&](uint4* b, int t) {    // lane-contiguous 1KB loads, L2-hot
#pragma unroll
    for (int ks = 0; ks < 8; ++ks)
      b[ks] = *(const uint4*)(Wpk + (((size_t)t * 8 + ks) * 64 + lane) * 8);
  };

  auto TILE = [&](const uint4* b, int t) {
    const int j0 = t * 16;
    f4 acc0 = {0.f,0.f,0.f,0.f}, acc1 = {0.f,0.f,0.f,0.f};
    f4 acc2 = {0.f,0.f,0.f,0.f}, acc3 = {0.f,0.f,0.f,0.f};
#pragma unroll
    for (int ks = 0; ks < 8; ++ks) {
      s8v bf = *(s8v*)&b[ks];
      acc0 = __builtin_amdgcn_mfma_f32_16x16x32_bf16(afr[0][ks], bf, acc0, 0, 0, 0);
      acc1 = __builtin_amdgcn_mfma_f32_16x16x32_bf16(afr[1][ks], bf, acc1, 0, 0, 0);
      acc2 = __builtin_amdgcn_mfma_f32_16x16x32_bf16(afr[2][ks], bf, acc2, 0, 0, 0);
      acc3 = __builtin_amdgcn_mfma_f32_16x16x32_bf16(afr[3][ks], bf, acc3, 0, 0, 0);
    }
    // transpose via per-wave LDS: D col=lane&15 (j), row=(lane>>4)*4+q (token)
#pragma unroll
    for (int q = 0; q < 4; ++q) {
      eps[ 0 + lgrp * 4 + q][lrow] = acc0[q];
      eps[16 + lgrp * 4 + q][lrow] = acc1[q];
      eps[32 + lgrp * 4 + q][lrow] = acc2[q];
      eps[48 + lgrp * 4 + q][lrow] = acc3[q];
    }
    // coalesced stores: 16 rows x 64B full-line chunks per instr (r22-proven)
    const f4 bv = *(const f4*)(bias + j0 + (lane & 3) * 4);
#pragma unroll
    for (int sw = 0; sw < 4; ++sw) {
      const int rr = sw * 16 + (lane >> 2);
      f4 v = *(const f4*)(&eps[rr][(lane & 3) * 4]);
      f4 o;
      o.x = v.x + bv.x; o.y = v.y + bv.y; o.z = v.z + bv.z; o.w = v.w + bv.w;
      *(f4*)(out + (tb + rr) * OUT_D + j0 + (lane & 3) * 4) = o;
    }
  };

  // ---- ping-pong over this wave's 36 tiles (k = wv + 4i within the half) ----
  uint4 bA[8], bB[8];
  loadW(bA, base + wv);
#pragma unroll 1
  for (int i = 0; i < 36; i += 2) {
    const int ta = base + wv + 4 * i;
    loadW(bB, ta + 4);                   // prefetch tile k=i+1
    TILE(bA, ta);                        // compute/store tile k=i
    if (i + 2 < 36) loadW(bA, ta + 8);   // prefetch tile k=i+2
    TILE(bB, ta + 4);                    // compute/store tile k=i+1
  }
}

// ---------------- fallback (ws too small): r13 fused fp32 kernel ----------------
namespace {
constexpr int TTF  = 16;
constexpr int XROW = IN_D + 4;
constexpr int TPAD = 4 * MM + 4;
}
template <int P4M>
__device__ __forceinline__ void phaseA_f(const float* xls, const float* Lrow0, float* t1w)
{
  float acc[17];
#pragma unroll
  for (int li = 0; li < 17; ++li) acc[li] = 0.f;
#pragma unroll 1
  for (int p4 = 0; p4 < P4M; ++p4) {
    f4 xv = *(const f4*)(xls + 4 * p4);
    f4 Lv[17];
#pragma unroll
    for (int li = 0; li < 17; ++li) Lv[li] = *(const f4*)(Lrow0 + (size_t)li * MM + 4 * p4);
#pragma unroll
    for (int li = 0; li < 17; ++li) {
      acc[li] = fmaf(xv.x, Lv[li].x, acc[li]); acc[li] = fmaf(xv.y, Lv[li].y, acc[li]);
      acc[li] = fmaf(xv.z, Lv[li].z, acc[li]); acc[li] = fmaf(xv.w, Lv[li].w, acc[li]);
    }
  }
#pragma unroll
  for (int li = 0; li < 17; ++li) t1w[li] = acc[li];
}
__global__ __launch_bounds__(NTH, 4)
void monarch_fused(const float* __restrict__ x, const float* __restrict__ L,
                   const float* __restrict__ R, const float* __restrict__ bias,
                   float* __restrict__ out)
{
  __shared__ float xs[TTF * XROW];
  __shared__ float t1s[TTF * TPAD];
  const int tid = threadIdx.x;
  const long tb = (long)blockIdx.x * TTF;
#pragma unroll
  for (int k = 0; k < (TTF * IN_D / 4) / NTH; ++k) {
    int i = k * NTH + tid; int tok = i >> 6; int pos = i & 63;
    *(f4*)(&xs[tok * XROW + 4 * pos]) = *(const f4*)(x + (tb + tok) * IN_D + 4 * pos);
  }
  __syncthreads();
  {
    const int tok = tid & 15; const int seg = tid >> 4;
    const int r = seg >> 2; const int lq = seg & 3;
    const float* xls = &xs[tok * XROW + r * MM];
    const float* Lrow0 = L + (size_t)(r * MM + lq * 17) * MM;
    float* t1w = &t1s[tok * TPAD + r * MM + lq * 17];
    if (r < 3) phaseA_f<17>(xls, Lrow0, t1w); else phaseA_f<13>(xls, Lrow0, t1w);
  }
  __syncthreads();
  {
    const int g = tid / 17; const int m = tid - g * 17; const int l4 = 4 * m;
#pragma unroll 1
    for (int j = 0; j < 5; ++j) {
      const int s = g + 15 * j;
      const bool act = (tid < 255) && (s < MM) && (s < MM - 1 || m < 13);
      const int scol = s * MM + l4;
      f4 R0, R1, R2, R3, bv;
      if (act) {
        R0 = *(const f4*)(R + (size_t)(l4 + 0) * (MM * MM) + (size_t)s * MM);
        R1 = *(const f4*)(R + (size_t)(l4 + 1) * (MM * MM) + (size_t)s * MM);
        R2 = *(const f4*)(R + (size_t)(l4 + 2) * (MM * MM) + (size_t)s * MM);
        R3 = *(const f4*)(R + (size_t)(l4 + 3) * (MM * MM) + (size_t)s * MM);
        bv = *(const f4*)(bias + scol);
      }
#pragma unroll 2
      for (int t = 0; t < TTF; ++t) {
        if (act) {
          const float* t1p = t1s + t * TPAD + l4;
          f4 a0 = *(const f4*)(t1p); f4 a1 = *(const f4*)(t1p + MM);
          f4 a2 = *(const f4*)(t1p + 2 * MM); f4 a3 = *(const f4*)(t1p + 3 * MM);
          f4 o;
          o.x = fmaf(a3.x, R0.w, fmaf(a2.x, R0.z, fmaf(a1.x, R0.y, fmaf(a0.x, R0.x, bv.x))));
          o.y = fmaf(a3.y, R1.w, fmaf(a2.y, R1.z, fmaf(a1.y, R1.y, fmaf(a0.y, R1.x, bv.y))));
          o.z = fmaf(a3.z, R2.w, fmaf(a2.z, R2.z, fmaf(a1.z, R2.y, fmaf(a0.z, R2.x, bv.z))));
          o.w = fmaf(a3.w, R3.w, fmaf(a2.w, R3.z, fmaf(a1.w, R3.y, fmaf(a0.w, R3.x, bv.w))));
          *(f4*)(out + (tb + t) * OUT_D + scol) = o;
        }
      }
    }
  }
}

extern "C" void kernel_launch(void* const* d_in, const int* in_sizes, int n_in,
                              void* d_out, int out_size, void* d_ws, size_t ws_size,
                              hipStream_t stream) {
  const float* x    = (const float*)d_in[0];
  const float* L    = (const float*)d_in[1];
  const float* R    = (const float*)d_in[2];
  const float* bias = (const float*)d_in[3];
  float* out = (float*)d_out;

  const int ntok = in_sizes[0] / IN_D;                       // 16384
  const size_t wb_bytes = (size_t)OUT_D * IN_D * sizeof(unsigned short);  // 2.36 MB

  if (ws_size >= wb_bytes) {
    unsigned short* Wpk = (unsigned short*)d_ws;
    pack_w2<<<576, NTH, 0, stream>>>(L, R, Wpk);             // 2304 frag-groups
    mono_gemm4<<<(ntok / BM) * 2, NTH, 0, stream>>>(x, Wpk, bias, out);
  } else {
    monarch_fused<<<ntok / TTF, NTH, 0, stream>>>(x, L, R, bias, out);
  }
}